// Round 2
// baseline (16688.672 us; speedup 1.0000x reference)
//
#include <hip/hip_runtime.h>
#include <cstdint>

#define T_STEPS 2048
#define HID 256

typedef _Float16 half8 __attribute__((ext_vector_type(8)));
typedef float f32x4 __attribute__((ext_vector_type(4)));

// tanh(x) = 1 - 2/(exp2(2*log2e*x)+1): 4 VALU ops (mul, exp, add+rcp, fma).
// Saturates correctly at +-inf.
__device__ __forceinline__ float tanh_fast(float x){
  float e = __builtin_amdgcn_exp2f(x * 2.8853900817779268f);
  float r = __builtin_amdgcn_rcpf(e + 1.0f);
  return __builtin_fmaf(-2.0f, r, 1.0f);
}

// Load 8 consecutive fp32, round-convert to an MFMA f16x8 fragment.
__device__ __forceinline__ half8 cvt_frag8(const float* __restrict__ p){
  float4 a = *(const float4*)p;
  float4 b = *(const float4*)(p + 4);
  half8 h;
  h[0]=(_Float16)a.x; h[1]=(_Float16)a.y; h[2]=(_Float16)a.z; h[3]=(_Float16)a.w;
  h[4]=(_Float16)b.x; h[5]=(_Float16)b.y; h[6]=(_Float16)b.z; h[7]=(_Float16)b.w;
  return h;
}

// ---------------------------------------------------------------------------
// gemm_xp: per 64-row tile t, xp[t][b][h] = x[t,b,:]·W[h,:] + b1[h] + b2[h].
// Orientation: A = W (m=hidden), B = x^T (n=batch) so D row=hidden, col=batch
// -- identical fragment layout to rec_layer's recurrence MFMA.
// Block = 512 thr = 8 waves; wave w: ng=w&1 (batches ng*32+nt*16), mg=w>>1
// (hidden mg*64+mt*16). Output fp32 in per-lane fragment order:
//   xp + t*16384 + w*2048 + lane*32 + (mt*2+nt)*4   (4 floats per frag)
// rec_layer loads these 8 dwordx4 directly as the kc=0 MFMA C operand.
// ---------------------------------------------------------------------------
template<bool A_IS_F32>
__global__ __launch_bounds__(512, 2) void gemm_xp(
    const void* __restrict__ Xin, const float* __restrict__ W,
    const float* __restrict__ b1, const float* __restrict__ b2,
    float* __restrict__ xp)
{
  const int t = blockIdx.x, tid = threadIdx.x;
  const int w = tid >> 6, l = tid & 63;
  const int ng = w & 1, mg = w >> 1;
  const int lm = l & 15, lq = l >> 4;

  half8 Af[4][8];
  #pragma unroll
  for (int mt = 0; mt < 4; ++mt){
    const int m = mg*64 + mt*16 + lm;
    #pragma unroll
    for (int kc = 0; kc < 8; ++kc)
      Af[mt][kc] = cvt_frag8(W + (long)m*HID + kc*32 + lq*8);
  }

  half8 Bf[2][8];
  #pragma unroll
  for (int nt = 0; nt < 2; ++nt){
    const long row = (long)t*64 + ng*32 + nt*16 + lm;
    #pragma unroll
    for (int kc = 0; kc < 8; ++kc){
      const int ko = kc*32 + lq*8;
      if (A_IS_F32) Bf[nt][kc] = cvt_frag8((const float*)Xin + row*HID + ko);
      else          Bf[nt][kc] = *(const half8*)((const _Float16*)Xin + row*HID + ko);
    }
  }

  f32x4 acc[4][2];
  #pragma unroll
  for (int mt = 0; mt < 4; ++mt)
    #pragma unroll
    for (int nt = 0; nt < 2; ++nt)
      acc[mt][nt] = (f32x4){0.f, 0.f, 0.f, 0.f};

  #pragma unroll
  for (int kc = 0; kc < 8; ++kc)
    #pragma unroll
    for (int mt = 0; mt < 4; ++mt)
      #pragma unroll
      for (int nt = 0; nt < 2; ++nt)
        acc[mt][nt] = __builtin_amdgcn_mfma_f32_16x16x32_f16(
            Af[mt][kc], Bf[nt][kc], acc[mt][nt], 0, 0, 0);

  float* dst = xp + (long)t*16384 + w*2048 + l*32;
  #pragma unroll
  for (int mt = 0; mt < 4; ++mt){
    const int h0 = mg*64 + mt*16 + lq*4;
    float4 bb1 = *(const float4*)(b1 + h0);
    float4 bb2 = *(const float4*)(b2 + h0);
    #pragma unroll
    for (int nt = 0; nt < 2; ++nt){
      f32x4 v = acc[mt][nt];
      v[0] += bb1.x + bb2.x; v[1] += bb1.y + bb2.y;
      v[2] += bb1.z + bb2.z; v[3] += bb1.w + bb2.w;
      *(f32x4*)(dst + (mt*2 + nt)*4) = v;
    }
  }
}

// ---------------------------------------------------------------------------
// rec_layer: h_t = tanh(xp[t] + Whh·h_{t-1}^T), one 512-thread block.
// A = Whh register-resident (128 VGPRs/wave); B = h_prev from LDS [batch][hid]
// (stride 264 f16, conflict-free ds_read_b128). xp tile enters as the C
// operand of the kc=0 MFMA (zero-VALU acc init); the freed C regs take the
// prefetch of tile t+1 immediately after kc=0. D fragment = 4 consecutive
// hidden at one batch -> ds_write_b64 to hbuf, dwordx4 fp32 out (layer 1),
// 8B f16 h_out (layer 0). ONE barrier per step (double-buffered hbuf).
// Alias safety (layer 1: xp lives in d_out): loads of tile t drain at the
// barrier ending step t-1 (compiler emits vmcnt(0) before s_barrier); stores
// to tile t happen in step t's epilogue, strictly after.
// ---------------------------------------------------------------------------
template<int LAYER>
__global__ __launch_bounds__(512, 2) void rec_layer(
    const float* __restrict__ xp, const float* __restrict__ Whh,
    _Float16* __restrict__ h_out, float* __restrict__ out)
{
  __shared__ __align__(16) _Float16 hbuf[2][64][264];
  const int tid = threadIdx.x;
  const int w = tid >> 6, l = tid & 63;
  const int ng = w & 1, mg = w >> 1;
  const int lm = l & 15, lq = l >> 4;

  // h_{-1} = 0 (t=0 reads buffer 1)
  for (int i = tid; i < 64*264; i += 512) (&hbuf[1][0][0])[i] = (_Float16)0.f;

  half8 Af[4][8];
  #pragma unroll
  for (int mt = 0; mt < 4; ++mt){
    const int m = mg*64 + mt*16 + lm;
    #pragma unroll
    for (int kc = 0; kc < 8; ++kc)
      Af[mt][kc] = cvt_frag8(Whh + (long)m*HID + kc*32 + lq*8);
  }
  __syncthreads();

  const float* xcur = xp + w*2048 + l*32;
  f32x4 xpf[4][2];
  #pragma unroll
  for (int mt = 0; mt < 4; ++mt)
    #pragma unroll
    for (int nt = 0; nt < 2; ++nt)
      xpf[mt][nt] = *(const f32x4*)(xcur + (mt*2 + nt)*4);
  __syncthreads();  // all waves' tile-0 loads complete before step-0 stores

  for (int t = 0; t < T_STEPS; ++t){
    const int pb = (t + 1) & 1, cb = t & 1;
    f32x4 acc[4][2];

    // kc = 0: C operand = xp[t] fragments
    {
      half8 B0 = *(const half8*)&hbuf[pb][ng*32      + lm][lq*8];
      half8 B1 = *(const half8*)&hbuf[pb][ng*32 + 16 + lm][lq*8];
      #pragma unroll
      for (int mt = 0; mt < 4; ++mt){
        acc[mt][0] = __builtin_amdgcn_mfma_f32_16x16x32_f16(Af[mt][0], B0, xpf[mt][0], 0,0,0);
        acc[mt][1] = __builtin_amdgcn_mfma_f32_16x16x32_f16(Af[mt][0], B1, xpf[mt][1], 0,0,0);
      }
    }

    // prefetch xp[t+1] into the freed C regs; drains at this step's barrier
    if (t + 1 < T_STEPS){
      const float* p = xcur + 16384;
      #pragma unroll
      for (int mt = 0; mt < 4; ++mt)
        #pragma unroll
        for (int nt = 0; nt < 2; ++nt)
          xpf[mt][nt] = *(const f32x4*)(p + (mt*2 + nt)*4);
      xcur = p;
    }

    #pragma unroll
    for (int kc = 1; kc < 8; ++kc){
      const int ko = kc*32 + lq*8;
      half8 B0 = *(const half8*)&hbuf[pb][ng*32      + lm][ko];
      half8 B1 = *(const half8*)&hbuf[pb][ng*32 + 16 + lm][ko];
      #pragma unroll
      for (int mt = 0; mt < 4; ++mt){
        acc[mt][0] = __builtin_amdgcn_mfma_f32_16x16x32_f16(Af[mt][kc], B0, acc[mt][0], 0,0,0);
        acc[mt][1] = __builtin_amdgcn_mfma_f32_16x16x32_f16(Af[mt][kc], B1, acc[mt][1], 0,0,0);
      }
    }

    // epilogue: tanh -> pack -> vectorized stores
    #pragma unroll
    for (int mt = 0; mt < 4; ++mt){
      const int h0 = mg*64 + mt*16 + lq*4;
      #pragma unroll
      for (int nt = 0; nt < 2; ++nt){
        const int b = ng*32 + nt*16 + lm;
        f32x4 v = acc[mt][nt];
        const float t0 = tanh_fast(v[0]), t1 = tanh_fast(v[1]);
        const float t2 = tanh_fast(v[2]), t3 = tanh_fast(v[3]);
        union { _Float16 h[4]; uint64_t u; } pk;
        pk.h[0]=(_Float16)t0; pk.h[1]=(_Float16)t1;
        pk.h[2]=(_Float16)t2; pk.h[3]=(_Float16)t3;
        *(uint64_t*)&hbuf[cb][b][h0] = pk.u;
        if (LAYER == 0)
          *(uint64_t*)(h_out + ((long)t*64 + b)*HID + h0) = pk.u;
        else {
          f32x4 o; o[0]=t0; o[1]=t1; o[2]=t2; o[3]=t3;
          *(f32x4*)(out + ((long)t*64 + b)*HID + h0) = o;
        }
      }
    }
    __syncthreads();  // the ONE barrier: orders hbuf wr->rd and drains vm
  }
}

// ---------------------------------------------------------------------------
// Buffers: xp0 fp32 frag-order (128 MiB) -> d_out (dead after rec<0>);
// h1 f16 row-major (64 MiB) -> d_ws; xp1 fp32 frag-order -> d_out, tile t
// exactly aliasing the step-t output region (consumed-before-store per the
// barrier argument above); final fp32 out -> d_out.
// ---------------------------------------------------------------------------
extern "C" void kernel_launch(void* const* d_in, const int* in_sizes, int n_in,
                              void* d_out, int out_size, void* d_ws, size_t ws_size,
                              hipStream_t stream)
{
  const float* x     = (const float*)d_in[0];
  const float* W_ih0 = (const float*)d_in[1];
  const float* W_hh0 = (const float*)d_in[2];
  const float* b_ih0 = (const float*)d_in[3];
  const float* b_hh0 = (const float*)d_in[4];
  const float* W_ih1 = (const float*)d_in[5];
  const float* W_hh1 = (const float*)d_in[6];
  const float* b_ih1 = (const float*)d_in[7];
  const float* b_hh1 = (const float*)d_in[8];

  float*    xp0 = (float*)d_out;
  float*    xp1 = (float*)d_out;
  _Float16* h1  = (_Float16*)d_ws;
  float*    out = (float*)d_out;

  gemm_xp<true ><<<T_STEPS, 512, 0, stream>>>(x,  W_ih0, b_ih0, b_hh0, xp0);
  rec_layer<0><<<1, 512, 0, stream>>>(xp0, W_hh0, h1, nullptr);
  gemm_xp<false><<<T_STEPS, 512, 0, stream>>>(h1, W_ih1, b_ih1, b_hh1, xp1);
  rec_layer<1><<<1, 512, 0, stream>>>(xp1, W_hh1, nullptr, out);
}

// Round 3
// 3553.191 us; speedup vs baseline: 4.6968x; 4.6968x over previous
//
#include <hip/hip_runtime.h>
#include <cstdint>

#define T_STEPS 2048
#define HID 256

typedef _Float16 half8 __attribute__((ext_vector_type(8)));
typedef float f32x4 __attribute__((ext_vector_type(4)));

// tanh(x) = 1 - 2/(exp2(2*log2e*x)+1): 4 VALU ops. Saturates at +-inf.
__device__ __forceinline__ float tanh_fast(float x){
  float e = __builtin_amdgcn_exp2f(x * 2.8853900817779268f);
  float r = __builtin_amdgcn_rcpf(e + 1.0f);
  return __builtin_fmaf(-2.0f, r, 1.0f);
}

// Load 8 consecutive fp32, round-convert to an MFMA f16x8 fragment.
__device__ __forceinline__ half8 cvt_frag8(const float* __restrict__ p){
  float4 a = *(const float4*)p;
  float4 b = *(const float4*)(p + 4);
  half8 h;
  h[0]=(_Float16)a.x; h[1]=(_Float16)a.y; h[2]=(_Float16)a.z; h[3]=(_Float16)a.w;
  h[4]=(_Float16)b.x; h[5]=(_Float16)b.y; h[6]=(_Float16)b.z; h[7]=(_Float16)b.w;
  return h;
}

// ---------------------------------------------------------------------------
// gemm_xp0: xp0[t,b,h] = x[t,b,:]·W_ih0[h,:] + b_ih0[h] + b_hh0[h], f16.
// A = W (m=hidden), B = x^T (n=batch); D row=hidden, col=batch.
// Output layout matches fused_rec's per-lane consumption exactly:
//   chunk(t,bi) = xp + (t*4 + bi)*4096 f16  (bi = batch/16)
//   lane (w = h>>5, l = lq*16+lm) holds 8 f16 at chunk + (w*64+l)*8:
//     element mt*4+r  ->  hidden w*32+mt*16+lq*4+r, batch bi*16+lm.
// One dwordx4 per (wp,nt) = fully coalesced 16B stores.
// ---------------------------------------------------------------------------
__global__ __launch_bounds__(512, 2) void gemm_xp0(
    const float* __restrict__ x, const float* __restrict__ W,
    const float* __restrict__ b1, const float* __restrict__ b2,
    _Float16* __restrict__ xp)
{
  const int t = blockIdx.x, tid = threadIdx.x;
  const int gw = tid >> 6, l = tid & 63;
  const int ng = gw & 1, mg = gw >> 1;
  const int lm = l & 15, lq = l >> 4;

  half8 Af[4][8];
  #pragma unroll
  for (int mt4 = 0; mt4 < 4; ++mt4)
    #pragma unroll
    for (int kc = 0; kc < 8; ++kc)
      Af[mt4][kc] = cvt_frag8(W + (long)(mg*64 + mt4*16 + lm)*HID + kc*32 + lq*8);

  half8 Bf[2][8];
  #pragma unroll
  for (int nt = 0; nt < 2; ++nt)
    #pragma unroll
    for (int kc = 0; kc < 8; ++kc)
      Bf[nt][kc] = cvt_frag8(x + ((long)t*64 + ng*32 + nt*16 + lm)*HID + kc*32 + lq*8);

  f32x4 acc[4][2];
  #pragma unroll
  for (int mt4 = 0; mt4 < 4; ++mt4)
    #pragma unroll
    for (int nt = 0; nt < 2; ++nt)
      acc[mt4][nt] = (f32x4){0.f,0.f,0.f,0.f};

  #pragma unroll
  for (int kc = 0; kc < 8; ++kc)
    #pragma unroll
    for (int mt4 = 0; mt4 < 4; ++mt4)
      #pragma unroll
      for (int nt = 0; nt < 2; ++nt)
        acc[mt4][nt] = __builtin_amdgcn_mfma_f32_16x16x32_f16(
            Af[mt4][kc], Bf[nt][kc], acc[mt4][nt], 0, 0, 0);

  _Float16* chunk0 = xp + ((long)t*4 + ng*2)*4096;
  #pragma unroll
  for (int wp = 0; wp < 2; ++wp){
    const int h0a = mg*64 + (2*wp    )*16 + lq*4;
    const int h0b = mg*64 + (2*wp + 1)*16 + lq*4;
    float4 ba1 = *(const float4*)(b1 + h0a), ba2 = *(const float4*)(b2 + h0a);
    float4 bb1 = *(const float4*)(b1 + h0b), bb2 = *(const float4*)(b2 + h0b);
    #pragma unroll
    for (int nt = 0; nt < 2; ++nt){
      f32x4 v0 = acc[2*wp][nt], v1 = acc[2*wp+1][nt];
      union { _Float16 h[8]; uint4 u; } pk;
      pk.h[0]=(_Float16)(v0[0]+ba1.x+ba2.x); pk.h[1]=(_Float16)(v0[1]+ba1.y+ba2.y);
      pk.h[2]=(_Float16)(v0[2]+ba1.z+ba2.z); pk.h[3]=(_Float16)(v0[3]+ba1.w+ba2.w);
      pk.h[4]=(_Float16)(v1[0]+bb1.x+bb2.x); pk.h[5]=(_Float16)(v1[1]+bb1.y+bb2.y);
      pk.h[6]=(_Float16)(v1[2]+bb1.z+bb2.z); pk.h[7]=(_Float16)(v1[3]+bb1.w+bb2.w);
      *(uint4*)(chunk0 + nt*4096 + ((mg*2 + wp)*64 + l)*8) = pk.u;
    }
  }
}

// ---------------------------------------------------------------------------
// fused_rec: both RNN layers, one block per 16-batch group (grid = 4).
// Per step t:  h1 = tanh(xp0[t] + Whh0·h1)          [GEMM0, 16 MFMA/wave]
//              h2 = tanh(b1+b2 + Wih1·h1 + Whh1·h2) [GEMM1+2, 32 MFMA/wave]
// Wave w owns hidden rows w*32..w*32+31 for all three GEMMs; A-fragments of
// Whh0/Wih1/Whh1 register-resident (3 x 64 VGPR). h1/h2 states live in LDS
// [16 batch][264 f16] double-buffered; B-fragments via ds_read_b128.
// Global traffic per step per block: 8 KB xp0 in (f16) + 8 KB h2 out (f16).
// Two barriers per step. h1 and xp1 never touch global memory.
// ---------------------------------------------------------------------------
__global__ __launch_bounds__(512, 2) void fused_rec(
    const _Float16* __restrict__ xp,
    const float* __restrict__ Whh0, const float* __restrict__ Wih1,
    const float* __restrict__ Whh1,
    const float* __restrict__ b1, const float* __restrict__ b2,
    _Float16* __restrict__ hout)
{
  __shared__ __align__(16) _Float16 h1b[2][16][264];
  __shared__ __align__(16) _Float16 h2b[2][16][264];
  const int bi = blockIdx.x, tid = threadIdx.x;
  const int w = tid >> 6, l = tid & 63;
  const int lm = l & 15, lq = l >> 4;

  // zero initial states (t=0 reads buffer index 1)
  for (int i = tid; i < 16*264; i += 512){
    (&h1b[1][0][0])[i] = (_Float16)0.f;
    (&h2b[1][0][0])[i] = (_Float16)0.f;
  }

  // register-resident A-fragments: rows w*32 + mt*16 + lm
  half8 A0[2][8], A1[2][8], A2[2][8];
  #pragma unroll
  for (int mt = 0; mt < 2; ++mt)
    #pragma unroll
    for (int kc = 0; kc < 8; ++kc){
      const long r = (long)(w*32 + mt*16 + lm)*HID + kc*32 + lq*8;
      A0[mt][kc] = cvt_frag8(Whh0 + r);
      A1[mt][kc] = cvt_frag8(Wih1 + r);
      A2[mt][kc] = cvt_frag8(Whh1 + r);
    }

  // layer-1 bias fragments (C operand of GEMM1's kc=0)
  f32x4 biasf[2];
  #pragma unroll
  for (int mt = 0; mt < 2; ++mt){
    const int h0 = w*32 + mt*16 + lq*4;
    f32x4 b;
    b[0]=b1[h0+0]+b2[h0+0]; b[1]=b1[h0+1]+b2[h0+1];
    b[2]=b1[h0+2]+b2[h0+2]; b[3]=b1[h0+3]+b2[h0+3];
    biasf[mt] = b;
  }
  __syncthreads();

  const _Float16* xptr = xp + (long)bi*4096 + (w*64 + l)*8;
  uint4 xv = *(const uint4*)xptr;
  _Float16* hob = hout + ((long)bi*16 + lm)*HID + w*32 + lq*4;

  for (int t = 0; t < T_STEPS; ++t){
    const int pb = (t + 1) & 1, cb = t & 1;

    // acc init from xp0 fragment (f16 -> f32)
    union { uint4 u; _Float16 h[8]; } xu; xu.u = xv;
    f32x4 a0, a1;
    a0[0]=(float)xu.h[0]; a0[1]=(float)xu.h[1]; a0[2]=(float)xu.h[2]; a0[3]=(float)xu.h[3];
    a1[0]=(float)xu.h[4]; a1[1]=(float)xu.h[5]; a1[2]=(float)xu.h[6]; a1[3]=(float)xu.h[7];

    // prefetch next step's xp (drains at this step's first barrier)
    if (t + 1 < T_STEPS){ xptr += 4*4096; xv = *(const uint4*)xptr; }

    // GEMM0: += Whh0 · h1_{t-1}
    #pragma unroll
    for (int kc = 0; kc < 8; ++kc){
      half8 B = *(const half8*)&h1b[pb][lm][kc*32 + lq*8];
      a0 = __builtin_amdgcn_mfma_f32_16x16x32_f16(A0[0][kc], B, a0, 0,0,0);
      a1 = __builtin_amdgcn_mfma_f32_16x16x32_f16(A0[1][kc], B, a1, 0,0,0);
    }

    // h1 = tanh(.)  -> LDS (B-operand layout for GEMM1)
    {
      union { _Float16 h[4]; uint64_t u; } p0, p1;
      p0.h[0]=(_Float16)tanh_fast(a0[0]); p0.h[1]=(_Float16)tanh_fast(a0[1]);
      p0.h[2]=(_Float16)tanh_fast(a0[2]); p0.h[3]=(_Float16)tanh_fast(a0[3]);
      p1.h[0]=(_Float16)tanh_fast(a1[0]); p1.h[1]=(_Float16)tanh_fast(a1[1]);
      p1.h[2]=(_Float16)tanh_fast(a1[2]); p1.h[3]=(_Float16)tanh_fast(a1[3]);
      *(uint64_t*)&h1b[cb][lm][w*32      + lq*4] = p0.u;
      *(uint64_t*)&h1b[cb][lm][w*32 + 16 + lq*4] = p1.u;
    }
    __syncthreads();  // h1_t visible to all waves

    // GEMM1+2: acc = bias ; += Wih1·h1_t ; += Whh1·h2_{t-1}
    a0 = biasf[0]; a1 = biasf[1];
    #pragma unroll
    for (int kc = 0; kc < 8; ++kc){
      half8 B = *(const half8*)&h1b[cb][lm][kc*32 + lq*8];
      a0 = __builtin_amdgcn_mfma_f32_16x16x32_f16(A1[0][kc], B, a0, 0,0,0);
      a1 = __builtin_amdgcn_mfma_f32_16x16x32_f16(A1[1][kc], B, a1, 0,0,0);
    }
    #pragma unroll
    for (int kc = 0; kc < 8; ++kc){
      half8 B = *(const half8*)&h2b[pb][lm][kc*32 + lq*8];
      a0 = __builtin_amdgcn_mfma_f32_16x16x32_f16(A2[0][kc], B, a0, 0,0,0);
      a1 = __builtin_amdgcn_mfma_f32_16x16x32_f16(A2[1][kc], B, a1, 0,0,0);
    }

    // h2 = tanh(.) -> LDS state + global out (f16)
    {
      union { _Float16 h[4]; uint64_t u; } q0, q1;
      q0.h[0]=(_Float16)tanh_fast(a0[0]); q0.h[1]=(_Float16)tanh_fast(a0[1]);
      q0.h[2]=(_Float16)tanh_fast(a0[2]); q0.h[3]=(_Float16)tanh_fast(a0[3]);
      q1.h[0]=(_Float16)tanh_fast(a1[0]); q1.h[1]=(_Float16)tanh_fast(a1[1]);
      q1.h[2]=(_Float16)tanh_fast(a1[2]); q1.h[3]=(_Float16)tanh_fast(a1[3]);
      *(uint64_t*)&h2b[cb][lm][w*32      + lq*4] = q0.u;
      *(uint64_t*)&h2b[cb][lm][w*32 + 16 + lq*4] = q1.u;
      _Float16* o = hob + (long)t*64*HID;
      *(uint64_t*)o        = q0.u;
      *(uint64_t*)(o + 16) = q1.u;
    }
    __syncthreads();  // h2_t + buffer rotation safety
  }
}

// f16 -> fp32 final output, full-device, HBM-bound (~192 MiB moved).
__global__ __launch_bounds__(256) void cvt_out(
    const _Float16* __restrict__ hin, float* __restrict__ out)
{
  const long i = ((long)blockIdx.x*256 + threadIdx.x)*8;
  half8 v = *(const half8*)(hin + i);
  float4 a, b;
  a.x=(float)v[0]; a.y=(float)v[1]; a.z=(float)v[2]; a.w=(float)v[3];
  b.x=(float)v[4]; b.y=(float)v[5]; b.z=(float)v[6]; b.w=(float)v[7];
  *(float4*)(out + i)     = a;
  *(float4*)(out + i + 4) = b;
}

// ---------------------------------------------------------------------------
// Buffers: xp0 f16 (64 MiB) -> d_out low half (dead before cvt_out runs);
// h2 f16 (64 MiB) -> d_ws; final fp32 -> d_out.
// ---------------------------------------------------------------------------
extern "C" void kernel_launch(void* const* d_in, const int* in_sizes, int n_in,
                              void* d_out, int out_size, void* d_ws, size_t ws_size,
                              hipStream_t stream)
{
  const float* x     = (const float*)d_in[0];
  const float* W_ih0 = (const float*)d_in[1];
  const float* W_hh0 = (const float*)d_in[2];
  const float* b_ih0 = (const float*)d_in[3];
  const float* b_hh0 = (const float*)d_in[4];
  const float* W_ih1 = (const float*)d_in[5];
  const float* W_hh1 = (const float*)d_in[6];
  const float* b_ih1 = (const float*)d_in[7];
  const float* b_hh1 = (const float*)d_in[8];

  _Float16* xp0 = (_Float16*)d_out;
  _Float16* h2  = (_Float16*)d_ws;

  gemm_xp0<<<T_STEPS, 512, 0, stream>>>(x, W_ih0, b_ih0, b_hh0, xp0);
  fused_rec<<<4, 512, 0, stream>>>(xp0, W_hh0, W_ih1, W_hh1, b_ih1, b_hh1, h2);
  cvt_out<<<(T_STEPS*64*HID)/(256*8), 256, 0, stream>>>(h2, (float*)d_out);
}